// Round 3
// baseline (803.716 us; speedup 1.0000x reference)
//
#include <hip/hip_runtime.h>
#include <hip/hip_bf16.h>

#define BATCH 1024
#define SEQ   256
#define CEMB  384
#define HD    64
#define LDK   72      // shK row stride (bf16) in attn kernel
#define LDV   264     // shVT row stride (bf16) in attn kernel
#define LDP   40      // per-wave P staging stride
#define LDSV  68      // qkv kernel v-transpose staging stride

#define SCALE 0.051031036307982884f   // 384^-0.5 (n_embed, not head_size)
#define LOG2E 1.4426950408889634f

typedef __bf16 bf16x8 __attribute__((ext_vector_type(8)));
typedef float  f32x4  __attribute__((ext_vector_type(4)));

// Repack fp32 Wq,Wk,Wv ([384 in][64 out] row-major) into bf16 Wt[3][64][384]
// (out-major) so MFMA B-fragments (n fixed, 8 consecutive k) are contiguous.
__global__ void repack_w_kernel(const float* __restrict__ Wq,
                                const float* __restrict__ Wk,
                                const float* __restrict__ Wv,
                                __bf16* __restrict__ Wt) {
    int idx = blockIdx.x * blockDim.x + threadIdx.x;
    if (idx >= 3 * HD * CEMB) return;
    int p   = idx / (HD * CEMB);
    int rem = idx - p * (HD * CEMB);
    int n   = rem / CEMB;
    int kk  = rem - n * CEMB;
    const float* W = (p == 0) ? Wq : (p == 1) ? Wk : Wv;
    Wt[idx] = (__bf16)W[kk * HD + n];
}

// ===== Kernel A: qkv = x @ {Wq,Wk,Wv}; q,k row-major bf16, v transposed =====
// 64 rows/block, 4 waves x 16 rows x 192 cols. Streaming, no big LDS ->
// ~4 blocks/CU, blocks at different phases give real latency hiding.
__launch_bounds__(256, 4)
__global__ void qkv_kernel(const float* __restrict__ x,
                           const __bf16* __restrict__ Wt,
                           __bf16* __restrict__ q,
                           __bf16* __restrict__ k,
                           __bf16* __restrict__ vT) {
    __shared__ __align__(16) __bf16 shV[64][LDSV];   // 8704 B v-transpose staging

    const int tid  = threadIdx.x;
    const int wave = tid >> 6;     // 0..3
    const int lane = tid & 63;
    const int q4   = lane >> 4;
    const int l15  = lane & 15;

    const int row0 = blockIdx.x * 64;   // global M row (= b*256 + t)
    const int b    = row0 >> 8;
    const int t0   = row0 & 255;

    const float*  xr = x  + (size_t)(row0 + wave * 16 + l15) * CEMB + q4 * 8;
    const __bf16* wb = Wt + (size_t)l15 * CEMB + q4 * 8;

    const f32x4 fzero = {0.f, 0.f, 0.f, 0.f};
    f32x4 acc[3][4];
    #pragma unroll
    for (int p = 0; p < 3; ++p)
        #pragma unroll
        for (int jn = 0; jn < 4; ++jn) acc[p][jn] = fzero;

    // K-loop, 12 steps of K=32; next step's x loads issued before current MFMA
    f32x4 lo = *(const f32x4*)(xr);
    f32x4 hi = *(const f32x4*)(xr + 4);
    #pragma unroll
    for (int step = 0; step < 12; ++step) {
        bf16x8 af;
        #pragma unroll
        for (int i = 0; i < 4; ++i) { af[i] = (__bf16)lo[i]; af[i + 4] = (__bf16)hi[i]; }
        if (step < 11) {
            lo = *(const f32x4*)(xr + (step + 1) * 32);
            hi = *(const f32x4*)(xr + (step + 1) * 32 + 4);
        }
        #pragma unroll
        for (int p = 0; p < 3; ++p)
            #pragma unroll
            for (int jn = 0; jn < 4; ++jn) {
                bf16x8 bfrag = *(const bf16x8*)(wb + (size_t)(p * HD + jn * 16) * CEMB + step * 32);
                acc[p][jn] = __builtin_amdgcn_mfma_f32_16x16x32_bf16(af, bfrag, acc[p][jn], 0, 0, 0);
            }
    }

    // q, k: bf16 stores, C-layout scatter (16-lane h-contiguous = 32B segments)
    {
        const size_t obase = (size_t)(row0 + wave * 16 + q4 * 4) * HD + l15;
        #pragma unroll
        for (int jn = 0; jn < 4; ++jn)
            #pragma unroll
            for (int r = 0; r < 4; ++r) {
                q[obase + (size_t)r * HD + jn * 16] = (__bf16)acc[0][jn][r];
                k[obase + (size_t)r * HD + jn * 16] = (__bf16)acc[1][jn][r];
            }
    }

    // v: transpose via LDS so vT global stores are coalesced 16B chunks
    #pragma unroll
    for (int jn = 0; jn < 4; ++jn)
        #pragma unroll
        for (int r = 0; r < 4; ++r)
            shV[wave * 16 + q4 * 4 + r][jn * 16 + l15] = (__bf16)acc[2][jn][r];
    __syncthreads();
    {
        const int h  = tid >> 2;   // 0..63
        const int tc = tid & 3;    // 0..3  (16-t chunk)
        bf16x8 o0, o1;
        #pragma unroll
        for (int i = 0; i < 8; ++i) {
            o0[i] = shV[tc * 16 + i][h];
            o1[i] = shV[tc * 16 + 8 + i][h];
        }
        __bf16* vp = vT + (size_t)(b * HD + h) * SEQ + t0 + tc * 16;
        *(bf16x8*)(vp)     = o0;
        *(bf16x8*)(vp + 8) = o1;
    }
}

// ===== Kernel B: causal attention from precomputed q,k,vT (bf16) =====
// 8 waves; wave owns t-tiles {wave, 15-wave}. q read straight from global in
// A-frag layout (row-major bf16 -> contiguous 16B fragment). k,vT -> LDS copy.
__launch_bounds__(512, 4)
__global__ void attn_kernel(const __bf16* __restrict__ q,
                            const __bf16* __restrict__ k,
                            const __bf16* __restrict__ vT,
                            float* __restrict__ out) {
    __shared__ __align__(16) __bf16 shK[SEQ][LDK];       // 36864 B
    __shared__ __align__(16) __bf16 shVT[HD][LDV];       // 33792 B
    __shared__ __align__(16) __bf16 stg8[8][16 * LDP];   // 10240 B P staging

    const int b    = blockIdx.x;
    const int tid  = threadIdx.x;
    const int wave = tid >> 6;
    const int lane = tid & 63;
    const int q4   = lane >> 4;
    const int l15  = lane & 15;

    const f32x4 fzero = {0.f, 0.f, 0.f, 0.f};
    const int mt_[2] = {wave, 15 - wave};

    // prefetch q A-frags from global (latency hidden under k/v staging)
    const __bf16* qb = q + (size_t)b * SEQ * HD;
    bf16x8 aq[2][2];
    #pragma unroll
    for (int m = 0; m < 2; ++m)
        #pragma unroll
        for (int hf = 0; hf < 2; ++hf)
            aq[m][hf] = *(const bf16x8*)(qb + (size_t)(mt_[m] * 16 + l15) * HD + hf * 32 + q4 * 8);

    // stage k (row-major, padded) and vT (row-major, padded) into LDS
    const __bf16* kb = k  + (size_t)b * SEQ * HD;
    const __bf16* vb = vT + (size_t)b * HD * SEQ;
    #pragma unroll
    for (int i = 0; i < 4; ++i) {
        int idx = i * 512 + tid;                         // 0..2047, 16B chunks
        bf16x8 kv = *(const bf16x8*)(kb + (size_t)idx * 8);
        *(bf16x8*)&shK[idx >> 3][(idx & 7) * 8] = kv;
        bf16x8 vv = *(const bf16x8*)(vb + (size_t)idx * 8);
        *(bf16x8*)&shVT[idx >> 5][(idx & 31) * 8] = vv;
    }
    __syncthreads();

    __bf16* stg = &stg8[wave][0];

    #pragma unroll
    for (int m = 0; m < 2; ++m) {
        const int mt = mt_[m];

        // ---- S = q_tile @ k^T (scaled), causal ----
        f32x4 accS[16];
        #pragma unroll
        for (int j = 0; j < 16; ++j) accS[j] = fzero;

        __builtin_amdgcn_s_setprio(1);
        #pragma unroll
        for (int j = 0; j < 16; ++j) {
            if (j <= mt) {
                bf16x8 bk0 = *(const bf16x8*)&shK[j * 16 + l15][q4 * 8];
                bf16x8 bk1 = *(const bf16x8*)&shK[j * 16 + l15][32 + q4 * 8];
                accS[j] = __builtin_amdgcn_mfma_f32_16x16x32_bf16(aq[m][0], bk0, accS[j], 0, 0, 0);
                accS[j] = __builtin_amdgcn_mfma_f32_16x16x32_bf16(aq[m][1], bk1, accS[j], 0, 0, 0);
            }
        }
        __builtin_amdgcn_s_setprio(0);

        // ---- softmax per row (16 lanes sharing q4, varying l15) ----
        float mx[4] = {-1e30f, -1e30f, -1e30f, -1e30f};
        #pragma unroll
        for (int j = 0; j < 16; ++j) {
            if (j > mt) continue;
            #pragma unroll
            for (int r = 0; r < 4; ++r) {
                float sv = accS[j][r] * SCALE;
                bool valid = (j < mt) || (l15 <= q4 * 4 + r);
                sv = valid ? sv : -1e30f;
                accS[j][r] = sv;
                mx[r] = fmaxf(mx[r], sv);
            }
        }
        #pragma unroll
        for (int off = 1; off < 16; off <<= 1)
            #pragma unroll
            for (int r = 0; r < 4; ++r)
                mx[r] = fmaxf(mx[r], __shfl_xor(mx[r], off, 64));

        float sm[4] = {0.f, 0.f, 0.f, 0.f};
        #pragma unroll
        for (int j = 0; j < 16; ++j) {
            if (j > mt) continue;
            #pragma unroll
            for (int r = 0; r < 4; ++r) {
                float pv = exp2f((accS[j][r] - mx[r]) * LOG2E);
                accS[j][r] = pv;
                sm[r] += pv;
            }
        }
        #pragma unroll
        for (int off = 1; off < 16; off <<= 1)
            #pragma unroll
            for (int r = 0; r < 4; ++r)
                sm[r] += __shfl_xor(sm[r], off, 64);
        float rinv[4];
        #pragma unroll
        for (int r = 0; r < 4; ++r) rinv[r] = 1.0f / sm[r];

        // ---- O = P @ v  (P: C-layout -> A-layout via per-wave LDS staging) ----
        f32x4 accO[4] = {fzero, fzero, fzero, fzero};
        const int ksmax = (mt * 16 + 15) >> 5;
        #pragma unroll
        for (int ks = 0; ks < 8; ++ks) {
            if (ks > ksmax) continue;
            __asm__ __volatile__("" ::: "memory");
            #pragma unroll
            for (int jj = 0; jj < 2; ++jj) {
                int j = 2 * ks + jj;
                #pragma unroll
                for (int r = 0; r < 4; ++r) {
                    float pv = (j <= mt) ? (float)accS[j][r] : 0.0f;
                    stg[(q4 * 4 + r) * LDP + jj * 16 + l15] = (__bf16)pv;
                }
            }
            // wave-internal LDS RAW: writes complete + no compiler reorder
            __asm__ __volatile__("s_waitcnt lgkmcnt(0)" ::: "memory");
            bf16x8 ap = *(const bf16x8*)(stg + l15 * LDP + q4 * 8);
            __builtin_amdgcn_s_setprio(1);
            #pragma unroll
            for (int hj = 0; hj < 4; ++hj) {
                bf16x8 bv = *(const bf16x8*)&shVT[hj * 16 + l15][ks * 32 + q4 * 8];
                accO[hj] = __builtin_amdgcn_mfma_f32_16x16x32_bf16(ap, bv, accO[hj], 0, 0, 0);
            }
            __builtin_amdgcn_s_setprio(0);
        }

        // ---- epilogue ----
        #pragma unroll
        for (int hj = 0; hj < 4; ++hj)
            #pragma unroll
            for (int r = 0; r < 4; ++r) {
                int t = mt * 16 + q4 * 4 + r;
                int h = hj * 16 + l15;
                out[((size_t)b * SEQ + t) * HD + h] = accO[hj][r] * rinv[r];
            }
    }
}

extern "C" void kernel_launch(void* const* d_in, const int* in_sizes, int n_in,
                              void* d_out, int out_size, void* d_ws, size_t ws_size,
                              hipStream_t stream) {
    const float* x  = (const float*)d_in[0];
    const float* Wq = (const float*)d_in[1];
    const float* Wk = (const float*)d_in[2];
    const float* Wv = (const float*)d_in[3];
    float* out = (float*)d_out;

    // workspace layout (bytes): Wt 147456 | q 33554432 | k 33554432 | vT 33554432
    char* ws = (char*)d_ws;
    __bf16* Wt = (__bf16*)ws;
    __bf16* q  = (__bf16*)(ws + 147456);
    __bf16* k  = (__bf16*)(ws + 147456 + 33554432);
    __bf16* vT = (__bf16*)(ws + 147456 + 2 * 33554432);

    repack_w_kernel<<<(3 * HD * CEMB + 255) / 256, 256, 0, stream>>>(Wq, Wk, Wv, Wt);
    qkv_kernel<<<(BATCH * SEQ) / 64, 256, 0, stream>>>(x, Wt, q, k, vT);
    attn_kernel<<<BATCH, 512, 0, stream>>>(q, k, vT, out);
}